// Round 20
// baseline (274.735 us; speedup 1.0000x reference)
//
#include <hip/hip_runtime.h>
#include <hip/hip_bf16.h>

#define N_NODES 20000
#define F_DIM 128
#define D_DIM 64
#define B_GR 8
#define E_EDGES 320000
#define A_ACT 512
#define NI_L 16
#define NCLS 16
#define NBUK 160          // buckets per graph
#define RPB  125          // rows per bucket
#define CAP  6144         // LDS payload capacity (edges); mean bucket = 2000
#define CAPW 320          // per-wave staged cw records (mean span 160, +12 sigma)

typedef __hip_bfloat16 bf16;
typedef unsigned long long ull;
typedef unsigned char uchar;
typedef __attribute__((ext_vector_type(8))) short bf16x8;
typedef __attribute__((ext_vector_type(4))) float f32x4;

static __device__ __forceinline__ short f2bf(float x) {
    __hip_bfloat16 h = __float2bfloat16(x);
    return *reinterpret_cast<short*>(&h);
}

// ---- imbb = bf16(nf @ w_n2l + bias + conv_b); h0b = bf16(relu(im)) ----
__global__ __launch_bounds__(256) void k_n2l(const float* __restrict__ nf,
        const float* __restrict__ w, const float* __restrict__ bias,
        const float* __restrict__ convb,
        bf16* __restrict__ imbb, bf16* __restrict__ h0b) {
    __shared__ float Wl[F_DIM * D_DIM];             // 32 KB
    for (int i = threadIdx.x; i < F_DIM * D_DIM; i += 256) Wl[i] = w[i];
    __syncthreads();
    int lane = threadIdx.x & 63;
    int wid = (blockIdx.x * 256 + threadIdx.x) >> 6;
    int nw  = (gridDim.x * 256) >> 6;
    float b = bias[lane];
    float cb = convb[lane];
    for (int n = wid; n < N_NODES; n += nw) {
        const float* nfr = nf + (size_t)n * F_DIM;
        float acc = b;
        #pragma unroll 8
        for (int k = 0; k < F_DIM; ++k)
            acc = fmaf(nfr[k], Wl[k * D_DIM + lane], acc);
        imbb[n * D_DIM + lane] = __float2bfloat16(acc + cb);
        h0b[n * D_DIM + lane] = __float2bfloat16(fmaxf(acc, 0.f));
    }
}

// ---- bucket histogram: bcnt[g][r/RPB] += 1 (int4 stream, LDS-aggregated) --
__global__ __launch_bounds__(256) void k_bcnt(const int* __restrict__ rows,
        int* __restrict__ bcnt) {
    __shared__ int lcnt[NBUK];
    for (int i = threadIdx.x; i < NBUK; i += 256) lcnt[i] = 0;
    __syncthreads();
    int g = blockIdx.x & 7;
    int chunk = blockIdx.x >> 3;
    int nb = gridDim.x >> 3;
    int per = (E_EDGES + nb - 1) / nb;              // 2500 (mult of 4)
    int e0 = chunk * per, e1 = min(e0 + per, E_EDGES);
    const int* rg = rows + (size_t)g * E_EDGES;
    for (int e = e0 + (int)threadIdx.x * 4; e < e1; e += 1024) {
        if (e + 3 < e1) {
            int4 r = *(const int4*)(rg + e);
            atomicAdd(&lcnt[r.x / RPB], 1);
            atomicAdd(&lcnt[r.y / RPB], 1);
            atomicAdd(&lcnt[r.z / RPB], 1);
            atomicAdd(&lcnt[r.w / RPB], 1);
        } else {
            for (int k = e; k < e1; ++k) atomicAdd(&lcnt[rg[k] / RPB], 1);
        }
    }
    __syncthreads();
    for (int i = threadIdx.x; i < NBUK; i += 256)
        if (lcnt[i]) atomicAdd(&bcnt[g * NBUK + i], lcnt[i]);
}

// ---- per-graph exclusive scan of 160 bucket counts ----
__global__ __launch_bounds__(256) void k_bscan(const int* __restrict__ bcnt,
        int* __restrict__ bptr, int* __restrict__ bcur) {
    int g = blockIdx.x;
    __shared__ int part[256];
    int t = threadIdx.x;
    int v = (t < NBUK) ? bcnt[g * NBUK + t] : 0;
    part[t] = v;
    __syncthreads();
    for (int off = 1; off < 256; off <<= 1) {
        int u = (t >= off) ? part[t - off] : 0;
        __syncthreads();
        part[t] += u;
        __syncthreads();
    }
    int excl = part[t] - v;
    if (t <= NBUK) bptr[g * (NBUK + 1) + t] = excl;
    if (t < NBUK)  bcur[g * NBUK + t] = excl;
}

// ---- partition edges into row buckets; emits FINAL 4B record + 1B row ----
__global__ __launch_bounds__(256) void k_part(const int* __restrict__ rows,
        const int* __restrict__ cols, const float* __restrict__ ew,
        int* __restrict__ bcur, unsigned* __restrict__ tA,
        uchar* __restrict__ tR) {
    int g = blockIdx.x & 7;
    int chunk = blockIdx.x >> 3;
    int nb = gridDim.x >> 3;
    int per = (E_EDGES + nb - 1) / nb;              // 2500
    int e0 = chunk * per, e1 = min(e0 + per, E_EDGES);
    const int*   rg = rows + (size_t)g * E_EDGES;
    const int*   cg = cols + (size_t)g * E_EDGES;
    const float* wg = ew   + (size_t)g * E_EDGES;
    unsigned* tAg = tA + (size_t)g * E_EDGES;
    uchar*    tRg = tR + (size_t)g * E_EDGES;
    __shared__ int lcnt[NBUK];
    __shared__ int lbase[NBUK];
    for (int base = e0; base < e1; base += 1024) {
        for (int i = threadIdx.x; i < NBUK; i += 256) lcnt[i] = 0;
        __syncthreads();
        int e = base + (int)threadIdx.x * 4;
        int r[4], c[4], bk[4], rk[4]; float w[4];
        #pragma unroll
        for (int j = 0; j < 4; ++j) bk[j] = -1;
        if (e + 3 < e1) {
            int4 r4 = *(const int4*)(rg + e);
            int4 c4 = *(const int4*)(cg + e);
            float4 w4 = *(const float4*)(wg + e);
            r[0]=r4.x; r[1]=r4.y; r[2]=r4.z; r[3]=r4.w;
            c[0]=c4.x; c[1]=c4.y; c[2]=c4.z; c[3]=c4.w;
            w[0]=w4.x; w[1]=w4.y; w[2]=w4.z; w[3]=w4.w;
            #pragma unroll
            for (int j = 0; j < 4; ++j) {
                bk[j] = r[j] / RPB;
                rk[j] = atomicAdd(&lcnt[bk[j]], 1);
            }
        } else {
            for (int j = 0; j < 4; ++j) {
                int k = e + j;
                if (k < e1) {
                    r[j] = rg[k]; c[j] = cg[k]; w[j] = wg[k];
                    bk[j] = r[j] / RPB;
                    rk[j] = atomicAdd(&lcnt[bk[j]], 1);
                }
            }
        }
        __syncthreads();
        for (int i = threadIdx.x; i < NBUK; i += 256)
            if (lcnt[i]) lbase[i] = atomicAdd(&bcur[g * NBUK + i], lcnt[i]);
        __syncthreads();
        #pragma unroll
        for (int j = 0; j < 4; ++j)
            if (bk[j] >= 0) {
                int pos = lbase[bk[j]] + rk[j];
                tAg[pos] = ((unsigned)(unsigned short)f2bf(w[j]) << 16)
                         | (unsigned)c[j];
                tRg[pos] = (uchar)(r[j] - bk[j] * RPB);
            }
        __syncthreads();
    }
}

// ---- CSR finalize per bucket: LDS sort -> sequential cw write + ptr ----
__global__ __launch_bounds__(256) void k_scat3(const unsigned* __restrict__ tA,
        const uchar* __restrict__ tR, const int* __restrict__ bptr,
        int* __restrict__ ptr, unsigned* __restrict__ cw) {
    __shared__ int hist[RPB];
    __shared__ int curs[RPB];
    __shared__ int part[128];
    __shared__ unsigned buf[CAP];                   // 24 KB
    int t = threadIdx.x;
    int g = blockIdx.x & 7;
    int b = blockIdx.x >> 3;
    int row0 = b * RPB;
    int e0 = bptr[g * (NBUK + 1) + b];
    int e1 = bptr[g * (NBUK + 1) + b + 1];
    int sz = e1 - e0;
    const unsigned* tAg = tA + (size_t)g * E_EDGES;
    const uchar*    tRg = tR + (size_t)g * E_EDGES;
    unsigned* cwg = cw + (size_t)g * E_EDGES;

    for (int i = t; i < RPB; i += 256) hist[i] = 0;
    __syncthreads();
    for (int e = e0 + t; e < e1; e += 256)
        atomicAdd(&hist[tRg[e]], 1);
    __syncthreads();
    if (t < 128) part[t] = (t < RPB) ? hist[t] : 0;
    __syncthreads();
    for (int off = 1; off < 128; off <<= 1) {
        int v = (t < 128 && t >= off) ? part[t - off] : 0;
        __syncthreads();
        if (t < 128) part[t] += v;
        __syncthreads();
    }
    if (t < RPB) {
        int excl = part[t] - hist[t];
        ptr[g * (N_NODES + 1) + row0 + t] = e0 + excl;
        curs[t] = excl;
    }
    if (b == NBUK - 1 && t == 0) ptr[g * (N_NODES + 1) + N_NODES] = e1;
    __syncthreads();

    if (sz <= CAP) {
        for (int e = e0 + t; e < e1; e += 256) {
            int pos = atomicAdd(&curs[tRg[e]], 1);
            buf[pos] = tAg[e];
        }
        __syncthreads();
        for (int i = t; i < sz; i += 256) cwg[e0 + i] = buf[i];
    } else {
        for (int e = e0 + t; e < e1; e += 256) {
            int pos = atomicAdd(&curs[tRg[e]], 1);
            cwg[e0 + pos] = tAg[e];
        }
    }
}

// ---- dense GEMM: dst[n][:] = bf16( src[n][:] @ conv_w ), per graph -------
template <int NGR>
__global__ __launch_bounds__(256) void k_gemm(const bf16* __restrict__ src,
        const float* __restrict__ convw, bf16* __restrict__ dst) {
    __shared__ __align__(16) short Wt[64 * 64];
    __shared__ __align__(16) float Cl[4][16 * 68];
    for (int i = threadIdx.x; i < 4096; i += 256) {
        int n = i >> 6, k = i & 63;
        Wt[(n << 6) | k] = f2bf(convw[(k << 6) | n]);
    }
    __syncthreads();
    int lane = threadIdx.x & 63;
    int wv   = threadIdx.x >> 6;
    int r    = lane & 15;
    int kg   = lane >> 4;
    bf16x8 Bf[4][2];
    #pragma unroll
    for (int t = 0; t < 4; ++t)
        #pragma unroll
        for (int s = 0; s < 2; ++s)
            Bf[t][s] = *(const bf16x8*)&Wt[(((t << 4) + r) << 6) + (s << 5) + (kg << 3)];

    int g = blockIdx.x & (NGR - 1);
    int chunk = blockIdx.x / NGR;
    int n0 = ((chunk << 2) + wv) << 4;
    if (n0 >= N_NODES) return;
    const bf16* sg = src + (size_t)g * N_NODES * D_DIM;
    bf16* dg = dst + (size_t)g * N_NODES * D_DIM;
    float* Cw = Cl[wv];

    f32x4 c0 = {0,0,0,0}, c1 = {0,0,0,0}, c2 = {0,0,0,0}, c3 = {0,0,0,0};
    #pragma unroll
    for (int s = 0; s < 2; ++s) {
        bf16x8 a = *(const bf16x8*)&sg[((n0 + r) << 6) + (s << 5) + (kg << 3)];
        c0 = __builtin_amdgcn_mfma_f32_16x16x32_bf16(a, Bf[0][s], c0, 0, 0, 0);
        c1 = __builtin_amdgcn_mfma_f32_16x16x32_bf16(a, Bf[1][s], c1, 0, 0, 0);
        c2 = __builtin_amdgcn_mfma_f32_16x16x32_bf16(a, Bf[2][s], c2, 0, 0, 0);
        c3 = __builtin_amdgcn_mfma_f32_16x16x32_bf16(a, Bf[3][s], c3, 0, 0, 0);
    }
    #pragma unroll
    for (int q = 0; q < 4; ++q) {
        Cw[((kg << 2) + q) * 68 +  0 + r] = c0[q];
        Cw[((kg << 2) + q) * 68 + 16 + r] = c1[q];
        Cw[((kg << 2) + q) * 68 + 32 + r] = c2[q];
        Cw[((kg << 2) + q) * 68 + 48 + r] = c3[q];
    }
    #pragma unroll
    for (int i = 0; i < 16; ++i)
        dg[((n0 + i) << 6) | lane] = __float2bfloat16(Cw[i * 68 + lane]);
}

// ---- gather level: h[n] = relu( Σ_e w·hW[c] + imb[n] ); optional ge sum --
// cw staged in per-wave LDS buffer (wave's edge span is contiguous).
// cw record = (bf16 w << 16) | col; addr = (col<<6)|lane; w = bitmask.
#define EDGE_FMA(U, A) { \
    float v_ = __bfloat162float(sg[(((size_t)((U) & 0xffffu)) << 6) | lane]); \
    A = fmaf(v_, __int_as_float((int)((U) & 0xffff0000u)), A); }

template <bool DO_GE, bool STORE_H>
__global__ __launch_bounds__(256) void k_gather(const bf16* __restrict__ hW,
        size_t src_stride, const int* __restrict__ ptr,
        const unsigned* __restrict__ cw, const bf16* __restrict__ imbb,
        bf16* __restrict__ hout, float* __restrict__ ge) {
    __shared__ unsigned cwbuf[4][CAPW];             // 5 KB
    int lane = threadIdx.x & 63;
    int wv   = threadIdx.x >> 6;
    int g    = blockIdx.x & 7;
    int chunk = blockIdx.x >> 3;
    const int CH = gridDim.x >> 3;
    int waves_per_graph = CH * 4;
    int npw = (N_NODES + waves_per_graph - 1) / waves_per_graph;
    int n0 = (chunk * 4 + wv) * npw;
    int n1 = min(n0 + npw, N_NODES);
    if (n0 >= n1) return;

    const bf16*     sg  = hW + (size_t)g * src_stride;
    const int*      pg  = ptr + g * (N_NODES + 1);
    const unsigned* cwg = cw + (size_t)g * E_EDGES;
    bf16* hg = hout + (size_t)g * N_NODES * D_DIM;
    float gsum = 0.f;

    int sb = pg[n0];
    int se = pg[n1];
    int span = se - sb;
    unsigned* wbuf = cwbuf[wv];

    if (span <= CAPW) {
        for (int i = lane; i < span; i += 64)
            wbuf[i] = cwg[sb + i];
        int s0 = sb;
        for (int n = n0; n < n1; ++n) {
            int s1 = pg[n + 1];
            float imv = __bfloat162float(imbb[(n << 6) | lane]);
            float a0 = 0.f, a1 = 0.f, a2 = 0.f, a3 = 0.f;
            int e = s0 - sb;
            int ee = s1 - sb;
            for (; e + 8 <= ee; e += 8) {
                unsigned u0 = wbuf[e],   u1 = wbuf[e+1], u2 = wbuf[e+2], u3 = wbuf[e+3];
                unsigned u4 = wbuf[e+4], u5 = wbuf[e+5], u6 = wbuf[e+6], u7 = wbuf[e+7];
                EDGE_FMA(u0, a0) EDGE_FMA(u1, a1) EDGE_FMA(u2, a2) EDGE_FMA(u3, a3)
                EDGE_FMA(u4, a0) EDGE_FMA(u5, a1) EDGE_FMA(u6, a2) EDGE_FMA(u7, a3)
            }
            for (; e + 2 <= ee; e += 2) {
                unsigned u0 = wbuf[e], u1 = wbuf[e+1];
                EDGE_FMA(u0, a0) EDGE_FMA(u1, a1)
            }
            if (e < ee) {
                unsigned u = wbuf[e];
                EDGE_FMA(u, a2)
            }
            s0 = s1;
            float hv = ((a0 + a1) + (a2 + a3)) + imv;
            hv = fmaxf(hv, 0.f);
            if (STORE_H) hg[((size_t)n << 6) | lane] = __float2bfloat16(hv);
            gsum += hv;
        }
    } else {
        int s0 = sb;
        for (int n = n0; n < n1; ++n) {
            int s1 = pg[n + 1];
            float imv = __bfloat162float(imbb[(n << 6) | lane]);
            float a0 = 0.f, a1 = 0.f, a2 = 0.f, a3 = 0.f;
            int e = s0;
            for (; e + 8 <= s1; e += 8) {
                unsigned u0 = cwg[e],   u1 = cwg[e+1], u2 = cwg[e+2], u3 = cwg[e+3];
                unsigned u4 = cwg[e+4], u5 = cwg[e+5], u6 = cwg[e+6], u7 = cwg[e+7];
                EDGE_FMA(u0, a0) EDGE_FMA(u1, a1) EDGE_FMA(u2, a2) EDGE_FMA(u3, a3)
                EDGE_FMA(u4, a0) EDGE_FMA(u5, a1) EDGE_FMA(u6, a2) EDGE_FMA(u7, a3)
            }
            for (; e + 2 <= s1; e += 2) {
                unsigned u0 = cwg[e], u1 = cwg[e+1];
                EDGE_FMA(u0, a0) EDGE_FMA(u1, a1)
            }
            if (e < s1) {
                unsigned u = cwg[e];
                EDGE_FMA(u, a2)
            }
            s0 = s1;
            float hv = ((a0 + a1) + (a2 + a3)) + imv;
            hv = fmaxf(hv, 0.f);
            if (STORE_H) hg[((size_t)n << 6) | lane] = __float2bfloat16(hv);
            gsum += hv;
        }
    }
    if (DO_GE) atomicAdd(&ge[g * D_DIM + lane], gsum);
}

// ---- level-1 h at action nodes ----
__global__ __launch_bounds__(256) void k_act(const bf16* __restrict__ hW,
        const int* __restrict__ ptr, const unsigned* __restrict__ cw,
        const bf16* __restrict__ imbb, const int* __restrict__ actions,
        float* __restrict__ act_emb) {
    int lane = threadIdx.x & 63;
    int wv   = threadIdx.x >> 6;
    int g    = blockIdx.x & 7;
    int a    = (blockIdx.x >> 3) * 4 + wv;
    int node = actions[(size_t)g * A_ACT + a];

    const bf16*     sg  = hW + (size_t)g * N_NODES * D_DIM;
    const int*      pg  = ptr + g * (N_NODES + 1);
    const unsigned* cwg = cw + (size_t)g * E_EDGES;
    int s0 = pg[node], s1 = pg[node + 1];
    float acc = 0.f;
    for (int e = s0; e < s1; ++e) {
        unsigned u = cwg[e];
        float v = __bfloat162float(sg[(((size_t)(u & 0xffffu)) << 6) | lane]);
        acc = fmaf(v, __int_as_float((int)(u & 0xffff0000u)), acc);
    }
    float hv = fmaxf(acc + __bfloat162float(imbb[(node << 6) | lane]), 0.f);
    act_emb[((size_t)g * A_ACT + a) * D_DIM + lane] = hv;
}

// ------- label embed + graph_embed mean finalize ----------
__global__ __launch_bounds__(512) void k_small(const int* __restrict__ labels,
        const float* __restrict__ le1w, const float* __restrict__ le1b,
        const float* __restrict__ le2w, const float* __restrict__ le2b,
        float* __restrict__ ge, float* __restrict__ le) {
    int b = threadIdx.x >> 6;
    int lane = threadIdx.x & 63;
    ge[b * D_DIM + lane] *= (1.f / (float)N_NODES);
    float x = le1b[lane];
    #pragma unroll
    for (int i = 0; i < NI_L; ++i) {
        int cls = labels[b * NI_L + i];
        x += le1w[(i * NCLS + cls) * D_DIM + lane];
    }
    x = fmaxf(x, 0.f);
    float acc = le2b[lane];
    for (int hh = 0; hh < D_DIM; ++hh)
        acc = fmaf(__shfl(x, hh), le2w[hh * D_DIM + lane], acc);
    le[b * D_DIM + lane] = fmaxf(acc, 0.f);
}

// ------- raw_pred[b,a] = linout(relu(lin1([ge,le,act]))) -------------
__global__ __launch_bounds__(256) void k_tail(const float* __restrict__ ge,
        const float* __restrict__ le, const float* __restrict__ act_emb,
        const float* __restrict__ lin1w, const float* __restrict__ lin1b,
        const float* __restrict__ loutw, const float* __restrict__ loutb,
        float* __restrict__ raw) {
    __shared__ float Wl[192 * 64];                  // 48 KB
    for (int i = threadIdx.x; i < 192 * 64; i += 256) Wl[i] = lin1w[i];
    __syncthreads();
    int lane = threadIdx.x & 63;
    int wv = blockIdx.x * 4 + (threadIdx.x >> 6);
    if (wv >= B_GR * A_ACT) return;
    int b = wv >> 9;
    float e2 = act_emb[(size_t)wv * D_DIM + lane];
    const float* geb = ge + b * D_DIM;
    const float* leb = le + b * D_DIM;
    float z = lin1b[lane];
    #pragma unroll 4
    for (int k = 0; k < 64; ++k) z = fmaf(geb[k], Wl[k * 64 + lane], z);
    #pragma unroll 4
    for (int k = 0; k < 64; ++k) z = fmaf(leb[k], Wl[(64 + k) * 64 + lane], z);
    #pragma unroll 4
    for (int k = 0; k < 64; ++k) z = fmaf(__shfl(e2, k), Wl[(128 + k) * 64 + lane], z);
    z = fmaxf(z, 0.f);
    float r = z * loutw[lane];
    #pragma unroll
    for (int off = 32; off; off >>= 1) r += __shfl_xor(r, off);
    if (lane == 0) raw[wv] = r + loutb[0];
}

// ---------------- preds[b] = max_a raw[b,a] ----------------
__global__ __launch_bounds__(512) void k_max(const float* __restrict__ raw,
        float* __restrict__ out) {
    int b = threadIdx.x >> 6, lane = threadIdx.x & 63;
    float m = -INFINITY;
    for (int a = lane; a < A_ACT; a += 64) m = fmaxf(m, raw[b * A_ACT + a]);
    #pragma unroll
    for (int off = 32; off; off >>= 1) m = fmaxf(m, __shfl_xor(m, off));
    if (lane == 0) out[b] = m;
}

extern "C" void kernel_launch(void* const* d_in, const int* in_sizes, int n_in,
                              void* d_out, int out_size, void* d_ws, size_t ws_size,
                              hipStream_t stream) {
    const float* nf      = (const float*)d_in[0];
    const float* w_n2l   = (const float*)d_in[1];
    const float* bias_n2l= (const float*)d_in[2];
    const float* conv_w  = (const float*)d_in[3];
    const float* conv_b  = (const float*)d_in[4];
    const float* lin1_w  = (const float*)d_in[5];
    const float* lin1_b  = (const float*)d_in[6];
    const float* linout_w= (const float*)d_in[7];
    const float* linout_b= (const float*)d_in[8];
    const float* le1_w   = (const float*)d_in[9];
    const float* le1_b   = (const float*)d_in[10];
    const float* le2_w   = (const float*)d_in[11];
    const float* le2_b   = (const float*)d_in[12];
    const float* edge_w  = (const float*)d_in[13];
    const int*   rows    = (const int*)d_in[14];
    const int*   cols    = (const int*)d_in[15];
    const int*   labels  = (const int*)d_in[16];
    const int*   actions = (const int*)d_in[17];
    float* out = (float*)d_out;

    const size_t NE = (size_t)N_NODES * D_DIM;      // 1.28 M elems

    // ---- workspace carve (~61 MB; 79.8 MB proven safe) ----
    unsigned* cw = (unsigned*)d_ws;                 // 10.24 MB (4B edge records)
    bf16*  h1   = (bf16*)(cw + (size_t)B_GR * E_EDGES);    // 20.5 MB
    unsigned* tA = (unsigned*)h1;                   // 10.24 MB (aliases h1)
    uchar*    tR = (uchar*)(tA + (size_t)B_GR * E_EDGES);  // 2.56 MB (aliases h1)
    bf16*  hW1  = h1 + 8 * NE;                      // 20.5 MB
    bf16*  imbb = hW1 + 8 * NE;                     // 2.56 MB
    bf16*  h0b  = imbb + NE;                        // 2.56 MB
    bf16*  hW0  = h0b + NE;                         // 2.56 MB
    float* act  = (float*)(hW0 + NE);               // 1 MB f32
    float* ge   = act + (size_t)B_GR * A_ACT * D_DIM;
    float* le   = ge + 512;
    float* raw  = le + 512;
    int*   bcnt = (int*)(raw + B_GR * A_ACT);       // 1280
    int*   bptr = bcnt + B_GR * NBUK;               // 1288
    int*   bcur = bptr + B_GR * (NBUK + 1);         // 1280
    int*   ptr  = bcur + B_GR * NBUK;               // 160008 (640 KB)

    // ---- prologue ----
    k_n2l<<<512, 256, 0, stream>>>(nf, w_n2l, bias_n2l, conv_b, imbb, h0b);
    hipMemsetAsync(bcnt, 0, (size_t)B_GR * NBUK * sizeof(int), stream);
    hipMemsetAsync(ge, 0, 512 * sizeof(float), stream);

    // ---- CSR build: bucket count -> scan -> partition -> LDS sort ----
    k_bcnt<<<1024, 256, 0, stream>>>(rows, bcnt);
    k_bscan<<<B_GR, 256, 0, stream>>>(bcnt, bptr, bcur);

    // hW0 = h0 @ W (independent of CSR build)
    k_gemm<1><<<313, 256, 0, stream>>>(h0b, conv_w, hW0);

    k_part<<<1024, 256, 0, stream>>>(rows, cols, edge_w, bcur, tA, tR);
    k_scat3<<<NBUK * 8, 256, 0, stream>>>(tA, tR, bptr, ptr, cw);

    // ---- level 0: h1 = relu(A_g @ hW0 + imb) ----
    k_gather<false, true><<<512 * 8, 256, 0, stream>>>(
            hW0, 0, ptr, cw, imbb, h1, nullptr);

    // hW1 = h1 @ W (per graph)
    k_gemm<8><<<313 * 8, 256, 0, stream>>>(h1, conv_w, hW1);

    // ---- level 1: ge += relu(A_g @ hW1 + imb), no store ----
    k_gather<true, false><<<512 * 8, 256, 0, stream>>>(
            hW1, NE, ptr, cw, imbb, nullptr, ge);

    // ---- level-1 h at action nodes ----
    k_act<<<(A_ACT / 4) * 8, 256, 0, stream>>>(hW1, ptr, cw, imbb, actions, act);

    // ---- tail ----
    k_small<<<1, 512, 0, stream>>>(labels, le1_w, le1_b, le2_w, le2_b, ge, le);
    k_tail<<<(B_GR * A_ACT) / 4, 256, 0, stream>>>(ge, le, act, lin1_w, lin1_b,
                                                   linout_w, linout_b, raw);
    k_max<<<1, 512, 0, stream>>>(raw, out);
}

// Round 21
// 273.297 us; speedup vs baseline: 1.0053x; 1.0053x over previous
//
#include <hip/hip_runtime.h>
#include <hip/hip_bf16.h>

#define N_NODES 20000
#define F_DIM 128
#define D_DIM 64
#define B_GR 8
#define E_EDGES 320000
#define A_ACT 512
#define NI_L 16
#define NCLS 16
#define NBUK 160          // buckets per graph
#define RPB  125          // rows per bucket
#define CAP  6144         // LDS payload capacity (edges); mean bucket = 2000
#define CAPW 320          // per-wave staged cw records (mean span 160, +12 sigma)

typedef __hip_bfloat16 bf16;
typedef unsigned long long ull;
typedef __attribute__((ext_vector_type(8))) short bf16x8;
typedef __attribute__((ext_vector_type(4))) float f32x4;

static __device__ __forceinline__ short f2bf(float x) {
    __hip_bfloat16 h = __float2bfloat16(x);
    return *reinterpret_cast<short*>(&h);
}

// ---- imbb = bf16(nf @ w_n2l + bias + conv_b); h0b = bf16(relu(im)) ----
__global__ __launch_bounds__(256) void k_n2l(const float* __restrict__ nf,
        const float* __restrict__ w, const float* __restrict__ bias,
        const float* __restrict__ convb,
        bf16* __restrict__ imbb, bf16* __restrict__ h0b) {
    __shared__ float Wl[F_DIM * D_DIM];             // 32 KB
    for (int i = threadIdx.x; i < F_DIM * D_DIM; i += 256) Wl[i] = w[i];
    __syncthreads();
    int lane = threadIdx.x & 63;
    int wid = (blockIdx.x * 256 + threadIdx.x) >> 6;
    int nw  = (gridDim.x * 256) >> 6;
    float b = bias[lane];
    float cb = convb[lane];
    for (int n = wid; n < N_NODES; n += nw) {
        const float* nfr = nf + (size_t)n * F_DIM;
        float acc = b;
        #pragma unroll 8
        for (int k = 0; k < F_DIM; ++k)
            acc = fmaf(nfr[k], Wl[k * D_DIM + lane], acc);
        imbb[n * D_DIM + lane] = __float2bfloat16(acc + cb);
        h0b[n * D_DIM + lane] = __float2bfloat16(fmaxf(acc, 0.f));
    }
}

// ---- bucket histogram: bcnt[g][r/RPB] += 1 (LDS-aggregated, int) ----
__global__ __launch_bounds__(256) void k_bcnt(const int* __restrict__ rows,
        int* __restrict__ bcnt) {
    __shared__ int lcnt[NBUK];
    for (int i = threadIdx.x; i < NBUK; i += 256) lcnt[i] = 0;
    __syncthreads();
    int g = blockIdx.x & 7;
    int chunk = blockIdx.x >> 3;
    int nb = gridDim.x >> 3;
    int per = (E_EDGES + nb - 1) / nb;
    int e0 = chunk * per, e1 = min(e0 + per, E_EDGES);
    const int* rg = rows + (size_t)g * E_EDGES;
    for (int e = e0 + (int)threadIdx.x; e < e1; e += 256)
        atomicAdd(&lcnt[rg[e] / RPB], 1);
    __syncthreads();
    for (int i = threadIdx.x; i < NBUK; i += 256)
        if (lcnt[i]) atomicAdd(&bcnt[g * NBUK + i], lcnt[i]);
}

// ---- per-graph exclusive scan of 160 bucket counts ----
__global__ __launch_bounds__(256) void k_bscan(const int* __restrict__ bcnt,
        int* __restrict__ bptr, int* __restrict__ bcur) {
    int g = blockIdx.x;
    __shared__ int part[256];
    int t = threadIdx.x;
    int v = (t < NBUK) ? bcnt[g * NBUK + t] : 0;
    part[t] = v;
    __syncthreads();
    for (int off = 1; off < 256; off <<= 1) {
        int u = (t >= off) ? part[t - off] : 0;
        __syncthreads();
        part[t] += u;
        __syncthreads();
    }
    int excl = part[t] - v;
    if (t <= NBUK) bptr[g * (NBUK + 1) + t] = excl;
    if (t < NBUK)  bcur[g * NBUK + t] = excl;
}

// ---- partition edges into row buckets (block-aggregated append) ----
__global__ __launch_bounds__(256) void k_part(const int* __restrict__ rows,
        const int* __restrict__ cols, const float* __restrict__ ew,
        int* __restrict__ bcur, float2* __restrict__ temp) {
    int g = blockIdx.x & 7;
    int chunk = blockIdx.x >> 3;
    int nb = gridDim.x >> 3;
    int per = (E_EDGES + nb - 1) / nb;
    int e0 = chunk * per, e1 = min(e0 + per, E_EDGES);
    const int*   rg = rows + (size_t)g * E_EDGES;
    const int*   cg = cols + (size_t)g * E_EDGES;
    const float* wg = ew   + (size_t)g * E_EDGES;
    float2* tg = temp + (size_t)g * E_EDGES;
    __shared__ int lcnt[NBUK];
    __shared__ int lbase[NBUK];
    for (int base = e0; base < e1; base += 1024) {
        for (int i = threadIdx.x; i < NBUK; i += 256) lcnt[i] = 0;
        __syncthreads();
        int r[4], c[4], bk[4], rk[4]; float w[4];
        #pragma unroll
        for (int j = 0; j < 4; ++j) {
            int e = base + (int)threadIdx.x + j * 256;
            if (e < e1) {
                r[j] = rg[e]; c[j] = cg[e]; w[j] = wg[e];
                bk[j] = r[j] / RPB;
                rk[j] = atomicAdd(&lcnt[bk[j]], 1);
            } else bk[j] = -1;
        }
        __syncthreads();
        for (int i = threadIdx.x; i < NBUK; i += 256)
            if (lcnt[i]) lbase[i] = atomicAdd(&bcur[g * NBUK + i], lcnt[i]);
        __syncthreads();
        #pragma unroll
        for (int j = 0; j < 4; ++j)
            if (bk[j] >= 0)
                tg[lbase[bk[j]] + rk[j]] =
                    make_float2(__int_as_float((r[j] << 15) | c[j]), w[j]);
        __syncthreads();
    }
}

// ---- CSR finalize per bucket: LDS sort -> sequential cw write + ptr ----
// cw record = (bf16 weight << 16) | col  (4 bytes per edge).
__global__ __launch_bounds__(256) void k_scat3(const float2* __restrict__ temp,
        const int* __restrict__ bptr, int* __restrict__ ptr,
        unsigned* __restrict__ cw) {
    __shared__ int hist[RPB];
    __shared__ int curs[RPB];
    __shared__ int part[128];
    __shared__ unsigned buf[CAP];                   // 24 KB
    int t = threadIdx.x;
    int g = blockIdx.x & 7;
    int b = blockIdx.x >> 3;
    int row0 = b * RPB;
    int e0 = bptr[g * (NBUK + 1) + b];
    int e1 = bptr[g * (NBUK + 1) + b + 1];
    int sz = e1 - e0;
    const float2* tg = temp + (size_t)g * E_EDGES;
    unsigned* cwg = cw + (size_t)g * E_EDGES;

    for (int i = t; i < RPB; i += 256) hist[i] = 0;
    __syncthreads();
    for (int e = e0 + t; e < e1; e += 256) {
        unsigned u = (unsigned)__float_as_int(tg[e].x);
        atomicAdd(&hist[(int)(u >> 15) - row0], 1);
    }
    __syncthreads();
    if (t < 128) part[t] = (t < RPB) ? hist[t] : 0;
    __syncthreads();
    for (int off = 1; off < 128; off <<= 1) {
        int v = (t < 128 && t >= off) ? part[t - off] : 0;
        __syncthreads();
        if (t < 128) part[t] += v;
        __syncthreads();
    }
    if (t < RPB) {
        int excl = part[t] - hist[t];
        ptr[g * (N_NODES + 1) + row0 + t] = e0 + excl;
        curs[t] = excl;
    }
    if (b == NBUK - 1 && t == 0) ptr[g * (N_NODES + 1) + N_NODES] = e1;
    __syncthreads();

    if (sz <= CAP) {
        for (int e = e0 + t; e < e1; e += 256) {
            float2 d = tg[e];
            unsigned u = (unsigned)__float_as_int(d.x);
            int pos = atomicAdd(&curs[(int)(u >> 15) - row0], 1);
            buf[pos] = ((unsigned)(unsigned short)f2bf(d.y) << 16) | (u & 32767u);
        }
        __syncthreads();
        for (int i = t; i < sz; i += 256) cwg[e0 + i] = buf[i];
    } else {
        for (int e = e0 + t; e < e1; e += 256) {
            float2 d = tg[e];
            unsigned u = (unsigned)__float_as_int(d.x);
            int pos = atomicAdd(&curs[(int)(u >> 15) - row0], 1);
            cwg[e0 + pos] = ((unsigned)(unsigned short)f2bf(d.y) << 16) | (u & 32767u);
        }
    }
}

// ---- dense GEMM: dst[n][:] = bf16( src[n][:] @ conv_w ), per graph -------
template <int NGR>
__global__ __launch_bounds__(256) void k_gemm(const bf16* __restrict__ src,
        const float* __restrict__ convw, bf16* __restrict__ dst) {
    __shared__ __align__(16) short Wt[64 * 64];
    __shared__ __align__(16) float Cl[4][16 * 68];
    for (int i = threadIdx.x; i < 4096; i += 256) {
        int n = i >> 6, k = i & 63;
        Wt[(n << 6) | k] = f2bf(convw[(k << 6) | n]);
    }
    __syncthreads();
    int lane = threadIdx.x & 63;
    int wv   = threadIdx.x >> 6;
    int r    = lane & 15;
    int kg   = lane >> 4;
    bf16x8 Bf[4][2];
    #pragma unroll
    for (int t = 0; t < 4; ++t)
        #pragma unroll
        for (int s = 0; s < 2; ++s)
            Bf[t][s] = *(const bf16x8*)&Wt[(((t << 4) + r) << 6) + (s << 5) + (kg << 3)];

    int g = blockIdx.x & (NGR - 1);
    int chunk = blockIdx.x / NGR;
    int n0 = ((chunk << 2) + wv) << 4;
    if (n0 >= N_NODES) return;
    const bf16* sg = src + (size_t)g * N_NODES * D_DIM;
    bf16* dg = dst + (size_t)g * N_NODES * D_DIM;
    float* Cw = Cl[wv];

    f32x4 c0 = {0,0,0,0}, c1 = {0,0,0,0}, c2 = {0,0,0,0}, c3 = {0,0,0,0};
    #pragma unroll
    for (int s = 0; s < 2; ++s) {
        bf16x8 a = *(const bf16x8*)&sg[((n0 + r) << 6) + (s << 5) + (kg << 3)];
        c0 = __builtin_amdgcn_mfma_f32_16x16x32_bf16(a, Bf[0][s], c0, 0, 0, 0);
        c1 = __builtin_amdgcn_mfma_f32_16x16x32_bf16(a, Bf[1][s], c1, 0, 0, 0);
        c2 = __builtin_amdgcn_mfma_f32_16x16x32_bf16(a, Bf[2][s], c2, 0, 0, 0);
        c3 = __builtin_amdgcn_mfma_f32_16x16x32_bf16(a, Bf[3][s], c3, 0, 0, 0);
    }
    #pragma unroll
    for (int q = 0; q < 4; ++q) {
        Cw[((kg << 2) + q) * 68 +  0 + r] = c0[q];
        Cw[((kg << 2) + q) * 68 + 16 + r] = c1[q];
        Cw[((kg << 2) + q) * 68 + 32 + r] = c2[q];
        Cw[((kg << 2) + q) * 68 + 48 + r] = c3[q];
    }
    #pragma unroll
    for (int i = 0; i < 16; ++i)
        dg[((n0 + i) << 6) | lane] = __float2bfloat16(Cw[i * 68 + lane]);
}

// ---- gather level: h[n] = relu( Σ_e w·hW[c] + imb[n] ); optional ge sum --
// cw staged in per-wave LDS buffer; 16 gathers in flight per batch (cheap
// LDS-sourced addresses). cw record = (bf16 w << 16) | col.
#define EDGE_FMA(U, A) { \
    float v_ = __bfloat162float(sg[(((size_t)((U) & 0xffffu)) << 6) | lane]); \
    A = fmaf(v_, __int_as_float((int)((U) & 0xffff0000u)), A); }

template <bool DO_GE, bool STORE_H>
__global__ __launch_bounds__(256) void k_gather(const bf16* __restrict__ hW,
        size_t src_stride, const int* __restrict__ ptr,
        const unsigned* __restrict__ cw, const bf16* __restrict__ imbb,
        bf16* __restrict__ hout, float* __restrict__ ge) {
    __shared__ unsigned cwbuf[4][CAPW];             // 5 KB
    int lane = threadIdx.x & 63;
    int wv   = threadIdx.x >> 6;
    int g    = blockIdx.x & 7;
    int chunk = blockIdx.x >> 3;
    const int CH = gridDim.x >> 3;
    int waves_per_graph = CH * 4;
    int npw = (N_NODES + waves_per_graph - 1) / waves_per_graph;
    int n0 = (chunk * 4 + wv) * npw;
    int n1 = min(n0 + npw, N_NODES);
    if (n0 >= n1) return;

    const bf16*     sg  = hW + (size_t)g * src_stride;
    const int*      pg  = ptr + g * (N_NODES + 1);
    const unsigned* cwg = cw + (size_t)g * E_EDGES;
    bf16* hg = hout + (size_t)g * N_NODES * D_DIM;
    float gsum = 0.f;

    int sb = pg[n0];
    int se = pg[n1];
    int span = se - sb;
    unsigned* wbuf = cwbuf[wv];

    if (span <= CAPW) {
        for (int i = lane; i < span; i += 64)
            wbuf[i] = cwg[sb + i];
        int s0 = sb;
        for (int n = n0; n < n1; ++n) {
            int s1 = pg[n + 1];
            float imv = __bfloat162float(imbb[(n << 6) | lane]);
            float a0 = 0.f, a1 = 0.f, a2 = 0.f, a3 = 0.f;
            int e = s0 - sb;
            int ee = s1 - sb;
            for (; e + 16 <= ee; e += 16) {         // 16 gathers in flight
                unsigned u0 = wbuf[e],    u1 = wbuf[e+1],  u2 = wbuf[e+2],  u3 = wbuf[e+3];
                unsigned u4 = wbuf[e+4],  u5 = wbuf[e+5],  u6 = wbuf[e+6],  u7 = wbuf[e+7];
                unsigned u8 = wbuf[e+8],  u9 = wbuf[e+9],  uA = wbuf[e+10], uB = wbuf[e+11];
                unsigned uC = wbuf[e+12], uD = wbuf[e+13], uE = wbuf[e+14], uF = wbuf[e+15];
                EDGE_FMA(u0, a0) EDGE_FMA(u1, a1) EDGE_FMA(u2, a2) EDGE_FMA(u3, a3)
                EDGE_FMA(u4, a0) EDGE_FMA(u5, a1) EDGE_FMA(u6, a2) EDGE_FMA(u7, a3)
                EDGE_FMA(u8, a0) EDGE_FMA(u9, a1) EDGE_FMA(uA, a2) EDGE_FMA(uB, a3)
                EDGE_FMA(uC, a0) EDGE_FMA(uD, a1) EDGE_FMA(uE, a2) EDGE_FMA(uF, a3)
            }
            for (; e + 8 <= ee; e += 8) {
                unsigned u0 = wbuf[e],   u1 = wbuf[e+1], u2 = wbuf[e+2], u3 = wbuf[e+3];
                unsigned u4 = wbuf[e+4], u5 = wbuf[e+5], u6 = wbuf[e+6], u7 = wbuf[e+7];
                EDGE_FMA(u0, a0) EDGE_FMA(u1, a1) EDGE_FMA(u2, a2) EDGE_FMA(u3, a3)
                EDGE_FMA(u4, a0) EDGE_FMA(u5, a1) EDGE_FMA(u6, a2) EDGE_FMA(u7, a3)
            }
            for (; e + 2 <= ee; e += 2) {
                unsigned u0 = wbuf[e], u1 = wbuf[e+1];
                EDGE_FMA(u0, a0) EDGE_FMA(u1, a1)
            }
            if (e < ee) {
                unsigned u = wbuf[e];
                EDGE_FMA(u, a2)
            }
            s0 = s1;
            float hv = ((a0 + a1) + (a2 + a3)) + imv;
            hv = fmaxf(hv, 0.f);
            if (STORE_H) hg[((size_t)n << 6) | lane] = __float2bfloat16(hv);
            gsum += hv;
        }
    } else {
        int s0 = sb;
        for (int n = n0; n < n1; ++n) {
            int s1 = pg[n + 1];
            float imv = __bfloat162float(imbb[(n << 6) | lane]);
            float a0 = 0.f, a1 = 0.f, a2 = 0.f, a3 = 0.f;
            int e = s0;
            for (; e + 8 <= s1; e += 8) {
                unsigned u0 = cwg[e],   u1 = cwg[e+1], u2 = cwg[e+2], u3 = cwg[e+3];
                unsigned u4 = cwg[e+4], u5 = cwg[e+5], u6 = cwg[e+6], u7 = cwg[e+7];
                EDGE_FMA(u0, a0) EDGE_FMA(u1, a1) EDGE_FMA(u2, a2) EDGE_FMA(u3, a3)
                EDGE_FMA(u4, a0) EDGE_FMA(u5, a1) EDGE_FMA(u6, a2) EDGE_FMA(u7, a3)
            }
            for (; e + 2 <= s1; e += 2) {
                unsigned u0 = cwg[e], u1 = cwg[e+1];
                EDGE_FMA(u0, a0) EDGE_FMA(u1, a1)
            }
            if (e < s1) {
                unsigned u = cwg[e];
                EDGE_FMA(u, a2)
            }
            s0 = s1;
            float hv = ((a0 + a1) + (a2 + a3)) + imv;
            hv = fmaxf(hv, 0.f);
            if (STORE_H) hg[((size_t)n << 6) | lane] = __float2bfloat16(hv);
            gsum += hv;
        }
    }
    if (DO_GE) atomicAdd(&ge[g * D_DIM + lane], gsum);
}

// ---- level-1 h at action nodes ----
__global__ __launch_bounds__(256) void k_act(const bf16* __restrict__ hW,
        const int* __restrict__ ptr, const unsigned* __restrict__ cw,
        const bf16* __restrict__ imbb, const int* __restrict__ actions,
        float* __restrict__ act_emb) {
    int lane = threadIdx.x & 63;
    int wv   = threadIdx.x >> 6;
    int g    = blockIdx.x & 7;
    int a    = (blockIdx.x >> 3) * 4 + wv;
    int node = actions[(size_t)g * A_ACT + a];

    const bf16*     sg  = hW + (size_t)g * N_NODES * D_DIM;
    const int*      pg  = ptr + g * (N_NODES + 1);
    const unsigned* cwg = cw + (size_t)g * E_EDGES;
    int s0 = pg[node], s1 = pg[node + 1];
    float acc = 0.f;
    for (int e = s0; e < s1; ++e) {
        unsigned u = cwg[e];
        float v = __bfloat162float(sg[(((size_t)(u & 0xffffu)) << 6) | lane]);
        acc = fmaf(v, __int_as_float((int)(u & 0xffff0000u)), acc);
    }
    float hv = fmaxf(acc + __bfloat162float(imbb[(node << 6) | lane]), 0.f);
    act_emb[((size_t)g * A_ACT + a) * D_DIM + lane] = hv;
}

// ------- label embed + graph_embed mean finalize ----------
__global__ __launch_bounds__(512) void k_small(const int* __restrict__ labels,
        const float* __restrict__ le1w, const float* __restrict__ le1b,
        const float* __restrict__ le2w, const float* __restrict__ le2b,
        float* __restrict__ ge, float* __restrict__ le) {
    int b = threadIdx.x >> 6;
    int lane = threadIdx.x & 63;
    ge[b * D_DIM + lane] *= (1.f / (float)N_NODES);
    float x = le1b[lane];
    #pragma unroll
    for (int i = 0; i < NI_L; ++i) {
        int cls = labels[b * NI_L + i];
        x += le1w[(i * NCLS + cls) * D_DIM + lane];
    }
    x = fmaxf(x, 0.f);
    float acc = le2b[lane];
    for (int hh = 0; hh < D_DIM; ++hh)
        acc = fmaf(__shfl(x, hh), le2w[hh * D_DIM + lane], acc);
    le[b * D_DIM + lane] = fmaxf(acc, 0.f);
}

// ------- raw_pred[b,a] = linout(relu(lin1([ge,le,act]))) -------------
__global__ __launch_bounds__(256) void k_tail(const float* __restrict__ ge,
        const float* __restrict__ le, const float* __restrict__ act_emb,
        const float* __restrict__ lin1w, const float* __restrict__ lin1b,
        const float* __restrict__ loutw, const float* __restrict__ loutb,
        float* __restrict__ raw) {
    __shared__ float Wl[192 * 64];                  // 48 KB
    for (int i = threadIdx.x; i < 192 * 64; i += 256) Wl[i] = lin1w[i];
    __syncthreads();
    int lane = threadIdx.x & 63;
    int wv = blockIdx.x * 4 + (threadIdx.x >> 6);
    if (wv >= B_GR * A_ACT) return;
    int b = wv >> 9;
    float e2 = act_emb[(size_t)wv * D_DIM + lane];
    const float* geb = ge + b * D_DIM;
    const float* leb = le + b * D_DIM;
    float z = lin1b[lane];
    #pragma unroll 4
    for (int k = 0; k < 64; ++k) z = fmaf(geb[k], Wl[k * 64 + lane], z);
    #pragma unroll 4
    for (int k = 0; k < 64; ++k) z = fmaf(leb[k], Wl[(64 + k) * 64 + lane], z);
    #pragma unroll 4
    for (int k = 0; k < 64; ++k) z = fmaf(__shfl(e2, k), Wl[(128 + k) * 64 + lane], z);
    z = fmaxf(z, 0.f);
    float r = z * loutw[lane];
    #pragma unroll
    for (int off = 32; off; off >>= 1) r += __shfl_xor(r, off);
    if (lane == 0) raw[wv] = r + loutb[0];
}

// ---------------- preds[b] = max_a raw[b,a] ----------------
__global__ __launch_bounds__(512) void k_max(const float* __restrict__ raw,
        float* __restrict__ out) {
    int b = threadIdx.x >> 6, lane = threadIdx.x & 63;
    float m = -INFINITY;
    for (int a = lane; a < A_ACT; a += 64) m = fmaxf(m, raw[b * A_ACT + a]);
    #pragma unroll
    for (int off = 32; off; off >>= 1) m = fmaxf(m, __shfl_xor(m, off));
    if (lane == 0) out[b] = m;
}

extern "C" void kernel_launch(void* const* d_in, const int* in_sizes, int n_in,
                              void* d_out, int out_size, void* d_ws, size_t ws_size,
                              hipStream_t stream) {
    const float* nf      = (const float*)d_in[0];
    const float* w_n2l   = (const float*)d_in[1];
    const float* bias_n2l= (const float*)d_in[2];
    const float* conv_w  = (const float*)d_in[3];
    const float* conv_b  = (const float*)d_in[4];
    const float* lin1_w  = (const float*)d_in[5];
    const float* lin1_b  = (const float*)d_in[6];
    const float* linout_w= (const float*)d_in[7];
    const float* linout_b= (const float*)d_in[8];
    const float* le1_w   = (const float*)d_in[9];
    const float* le1_b   = (const float*)d_in[10];
    const float* le2_w   = (const float*)d_in[11];
    const float* le2_b   = (const float*)d_in[12];
    const float* edge_w  = (const float*)d_in[13];
    const int*   rows    = (const int*)d_in[14];
    const int*   cols    = (const int*)d_in[15];
    const int*   labels  = (const int*)d_in[16];
    const int*   actions = (const int*)d_in[17];
    float* out = (float*)d_out;

    const size_t NE = (size_t)N_NODES * D_DIM;      // 1.28 M elems

    // ---- workspace carve (~61 MB; 79.8 MB proven safe) ----
    unsigned* cw = (unsigned*)d_ws;                 // 10.24 MB (4B edge records)
    bf16*  h1   = (bf16*)(cw + (size_t)B_GR * E_EDGES);    // 20.5 MB
    float2* temp = (float2*)h1;                     // aliases h1 (consumed pre-gather0)
    bf16*  hW1  = h1 + 8 * NE;                      // 20.5 MB
    bf16*  imbb = hW1 + 8 * NE;                     // 2.56 MB
    bf16*  h0b  = imbb + NE;                        // 2.56 MB
    bf16*  hW0  = h0b + NE;                         // 2.56 MB
    float* act  = (float*)(hW0 + NE);               // 1 MB f32
    float* ge   = act + (size_t)B_GR * A_ACT * D_DIM;
    float* le   = ge + 512;
    float* raw  = le + 512;
    int*   bcnt = (int*)(raw + B_GR * A_ACT);       // 1280
    int*   bptr = bcnt + B_GR * NBUK;               // 1288
    int*   bcur = bptr + B_GR * (NBUK + 1);         // 1280
    int*   ptr  = bcur + B_GR * NBUK;               // 160008 (640 KB)

    // ---- prologue ----
    k_n2l<<<512, 256, 0, stream>>>(nf, w_n2l, bias_n2l, conv_b, imbb, h0b);
    hipMemsetAsync(bcnt, 0, (size_t)B_GR * NBUK * sizeof(int), stream);
    hipMemsetAsync(ge, 0, 512 * sizeof(float), stream);

    // ---- CSR build: bucket count -> scan -> partition -> LDS sort ----
    k_bcnt<<<1024, 256, 0, stream>>>(rows, bcnt);
    k_bscan<<<B_GR, 256, 0, stream>>>(bcnt, bptr, bcur);

    // hW0 = h0 @ W (independent of CSR build)
    k_gemm<1><<<313, 256, 0, stream>>>(h0b, conv_w, hW0);

    k_part<<<1024, 256, 0, stream>>>(rows, cols, edge_w, bcur, temp);
    k_scat3<<<NBUK * 8, 256, 0, stream>>>(temp, bptr, ptr, cw);

    // ---- level 0: h1 = relu(A_g @ hW0 + imb) ----
    k_gather<false, true><<<512 * 8, 256, 0, stream>>>(
            hW0, 0, ptr, cw, imbb, h1, nullptr);

    // hW1 = h1 @ W (per graph)
    k_gemm<8><<<313 * 8, 256, 0, stream>>>(h1, conv_w, hW1);

    // ---- level 1: ge += relu(A_g @ hW1 + imb), no store ----
    k_gather<true, false><<<512 * 8, 256, 0, stream>>>(
            hW1, NE, ptr, cw, imbb, nullptr, ge);

    // ---- level-1 h at action nodes ----
    k_act<<<(A_ACT / 4) * 8, 256, 0, stream>>>(hW1, ptr, cw, imbb, actions, act);

    // ---- tail ----
    k_small<<<1, 512, 0, stream>>>(labels, le1_w, le1_b, le2_w, le2_b, ge, le);
    k_tail<<<(B_GR * A_ACT) / 4, 256, 0, stream>>>(ge, le, act, lin1_w, lin1_b,
                                                   linout_w, linout_b, raw);
    k_max<<<1, 512, 0, stream>>>(raw, out);
}

// Round 22
// 260.973 us; speedup vs baseline: 1.0527x; 1.0472x over previous
//
#include <hip/hip_runtime.h>
#include <hip/hip_bf16.h>

#define N_NODES 20000
#define F_DIM 128
#define D_DIM 64
#define B_GR 8
#define E_EDGES 320000
#define A_ACT 512
#define NI_L 16
#define NCLS 16
#define NBUK 160          // buckets per graph
#define RPB  125          // rows per bucket
#define CAP  6144         // LDS payload capacity (edges); mean bucket = 2000
#define CAPW 320          // per-wave staged cw records (mean span 160, +12 sigma)

typedef __hip_bfloat16 bf16;
typedef unsigned long long ull;
typedef __attribute__((ext_vector_type(8))) short bf16x8;
typedef __attribute__((ext_vector_type(4))) float f32x4;

static __device__ __forceinline__ short f2bf(float x) {
    __hip_bfloat16 h = __float2bfloat16(x);
    return *reinterpret_cast<short*>(&h);
}

// ---- imbb = bf16(nf @ w_n2l + bias + conv_b); h0b = bf16(relu(im)) ----
__global__ __launch_bounds__(256) void k_n2l(const float* __restrict__ nf,
        const float* __restrict__ w, const float* __restrict__ bias,
        const float* __restrict__ convb,
        bf16* __restrict__ imbb, bf16* __restrict__ h0b) {
    __shared__ float Wl[F_DIM * D_DIM];             // 32 KB
    for (int i = threadIdx.x; i < F_DIM * D_DIM; i += 256) Wl[i] = w[i];
    __syncthreads();
    int lane = threadIdx.x & 63;
    int wid = (blockIdx.x * 256 + threadIdx.x) >> 6;
    int nw  = (gridDim.x * 256) >> 6;
    float b = bias[lane];
    float cb = convb[lane];
    for (int n = wid; n < N_NODES; n += nw) {
        const float* nfr = nf + (size_t)n * F_DIM;
        float acc = b;
        #pragma unroll 8
        for (int k = 0; k < F_DIM; ++k)
            acc = fmaf(nfr[k], Wl[k * D_DIM + lane], acc);
        imbb[n * D_DIM + lane] = __float2bfloat16(acc + cb);
        h0b[n * D_DIM + lane] = __float2bfloat16(fmaxf(acc, 0.f));
    }
}

// ---- bucket histogram: bcnt[g][r/RPB] += 1 (LDS-aggregated, int) ----
__global__ __launch_bounds__(256) void k_bcnt(const int* __restrict__ rows,
        int* __restrict__ bcnt) {
    __shared__ int lcnt[NBUK];
    for (int i = threadIdx.x; i < NBUK; i += 256) lcnt[i] = 0;
    __syncthreads();
    int g = blockIdx.x & 7;
    int chunk = blockIdx.x >> 3;
    int nb = gridDim.x >> 3;
    int per = (E_EDGES + nb - 1) / nb;
    int e0 = chunk * per, e1 = min(e0 + per, E_EDGES);
    const int* rg = rows + (size_t)g * E_EDGES;
    for (int e = e0 + (int)threadIdx.x; e < e1; e += 256)
        atomicAdd(&lcnt[rg[e] / RPB], 1);
    __syncthreads();
    for (int i = threadIdx.x; i < NBUK; i += 256)
        if (lcnt[i]) atomicAdd(&bcnt[g * NBUK + i], lcnt[i]);
}

// ---- per-graph exclusive scan of 160 bucket counts ----
__global__ __launch_bounds__(256) void k_bscan(const int* __restrict__ bcnt,
        int* __restrict__ bptr, int* __restrict__ bcur) {
    int g = blockIdx.x;
    __shared__ int part[256];
    int t = threadIdx.x;
    int v = (t < NBUK) ? bcnt[g * NBUK + t] : 0;
    part[t] = v;
    __syncthreads();
    for (int off = 1; off < 256; off <<= 1) {
        int u = (t >= off) ? part[t - off] : 0;
        __syncthreads();
        part[t] += u;
        __syncthreads();
    }
    int excl = part[t] - v;
    if (t <= NBUK) bptr[g * (NBUK + 1) + t] = excl;
    if (t < NBUK)  bcur[g * NBUK + t] = excl;
}

// ---- partition edges into row buckets (block-aggregated append) ----
__global__ __launch_bounds__(256) void k_part(const int* __restrict__ rows,
        const int* __restrict__ cols, const float* __restrict__ ew,
        int* __restrict__ bcur, float2* __restrict__ temp) {
    int g = blockIdx.x & 7;
    int chunk = blockIdx.x >> 3;
    int nb = gridDim.x >> 3;
    int per = (E_EDGES + nb - 1) / nb;
    int e0 = chunk * per, e1 = min(e0 + per, E_EDGES);
    const int*   rg = rows + (size_t)g * E_EDGES;
    const int*   cg = cols + (size_t)g * E_EDGES;
    const float* wg = ew   + (size_t)g * E_EDGES;
    float2* tg = temp + (size_t)g * E_EDGES;
    __shared__ int lcnt[NBUK];
    __shared__ int lbase[NBUK];
    for (int base = e0; base < e1; base += 1024) {
        for (int i = threadIdx.x; i < NBUK; i += 256) lcnt[i] = 0;
        __syncthreads();
        int r[4], c[4], bk[4], rk[4]; float w[4];
        #pragma unroll
        for (int j = 0; j < 4; ++j) {
            int e = base + (int)threadIdx.x + j * 256;
            if (e < e1) {
                r[j] = rg[e]; c[j] = cg[e]; w[j] = wg[e];
                bk[j] = r[j] / RPB;
                rk[j] = atomicAdd(&lcnt[bk[j]], 1);
            } else bk[j] = -1;
        }
        __syncthreads();
        for (int i = threadIdx.x; i < NBUK; i += 256)
            if (lcnt[i]) lbase[i] = atomicAdd(&bcur[g * NBUK + i], lcnt[i]);
        __syncthreads();
        #pragma unroll
        for (int j = 0; j < 4; ++j)
            if (bk[j] >= 0)
                tg[lbase[bk[j]] + rk[j]] =
                    make_float2(__int_as_float((r[j] << 15) | c[j]), w[j]);
        __syncthreads();
    }
}

// ---- CSR finalize per bucket: LDS sort -> sequential cw write + ptr ----
// cw record = (bf16 weight << 16) | col  (4 bytes per edge).
__global__ __launch_bounds__(256) void k_scat3(const float2* __restrict__ temp,
        const int* __restrict__ bptr, int* __restrict__ ptr,
        unsigned* __restrict__ cw) {
    __shared__ int hist[RPB];
    __shared__ int curs[RPB];
    __shared__ int part[128];
    __shared__ unsigned buf[CAP];                   // 24 KB
    int t = threadIdx.x;
    int g = blockIdx.x & 7;
    int b = blockIdx.x >> 3;
    int row0 = b * RPB;
    int e0 = bptr[g * (NBUK + 1) + b];
    int e1 = bptr[g * (NBUK + 1) + b + 1];
    int sz = e1 - e0;
    const float2* tg = temp + (size_t)g * E_EDGES;
    unsigned* cwg = cw + (size_t)g * E_EDGES;

    for (int i = t; i < RPB; i += 256) hist[i] = 0;
    __syncthreads();
    for (int e = e0 + t; e < e1; e += 256) {
        unsigned u = (unsigned)__float_as_int(tg[e].x);
        atomicAdd(&hist[(int)(u >> 15) - row0], 1);
    }
    __syncthreads();
    if (t < 128) part[t] = (t < RPB) ? hist[t] : 0;
    __syncthreads();
    for (int off = 1; off < 128; off <<= 1) {
        int v = (t < 128 && t >= off) ? part[t - off] : 0;
        __syncthreads();
        if (t < 128) part[t] += v;
        __syncthreads();
    }
    if (t < RPB) {
        int excl = part[t] - hist[t];
        ptr[g * (N_NODES + 1) + row0 + t] = e0 + excl;
        curs[t] = excl;
    }
    if (b == NBUK - 1 && t == 0) ptr[g * (N_NODES + 1) + N_NODES] = e1;
    __syncthreads();

    if (sz <= CAP) {
        for (int e = e0 + t; e < e1; e += 256) {
            float2 d = tg[e];
            unsigned u = (unsigned)__float_as_int(d.x);
            int pos = atomicAdd(&curs[(int)(u >> 15) - row0], 1);
            buf[pos] = ((unsigned)(unsigned short)f2bf(d.y) << 16) | (u & 32767u);
        }
        __syncthreads();
        for (int i = t; i < sz; i += 256) cwg[e0 + i] = buf[i];
    } else {
        for (int e = e0 + t; e < e1; e += 256) {
            float2 d = tg[e];
            unsigned u = (unsigned)__float_as_int(d.x);
            int pos = atomicAdd(&curs[(int)(u >> 15) - row0], 1);
            cwg[e0 + pos] = ((unsigned)(unsigned short)f2bf(d.y) << 16) | (u & 32767u);
        }
    }
}

// ---- dense GEMM: dst[n][:] = bf16( src[n][:] @ conv_w ), per graph -------
template <int NGR>
__global__ __launch_bounds__(256) void k_gemm(const bf16* __restrict__ src,
        const float* __restrict__ convw, bf16* __restrict__ dst) {
    __shared__ __align__(16) short Wt[64 * 64];
    __shared__ __align__(16) float Cl[4][16 * 68];
    for (int i = threadIdx.x; i < 4096; i += 256) {
        int n = i >> 6, k = i & 63;
        Wt[(n << 6) | k] = f2bf(convw[(k << 6) | n]);
    }
    __syncthreads();
    int lane = threadIdx.x & 63;
    int wv   = threadIdx.x >> 6;
    int r    = lane & 15;
    int kg   = lane >> 4;
    bf16x8 Bf[4][2];
    #pragma unroll
    for (int t = 0; t < 4; ++t)
        #pragma unroll
        for (int s = 0; s < 2; ++s)
            Bf[t][s] = *(const bf16x8*)&Wt[(((t << 4) + r) << 6) + (s << 5) + (kg << 3)];

    int g = blockIdx.x & (NGR - 1);
    int chunk = blockIdx.x / NGR;
    int n0 = ((chunk << 2) + wv) << 4;
    if (n0 >= N_NODES) return;
    const bf16* sg = src + (size_t)g * N_NODES * D_DIM;
    bf16* dg = dst + (size_t)g * N_NODES * D_DIM;
    float* Cw = Cl[wv];

    f32x4 c0 = {0,0,0,0}, c1 = {0,0,0,0}, c2 = {0,0,0,0}, c3 = {0,0,0,0};
    #pragma unroll
    for (int s = 0; s < 2; ++s) {
        bf16x8 a = *(const bf16x8*)&sg[((n0 + r) << 6) + (s << 5) + (kg << 3)];
        c0 = __builtin_amdgcn_mfma_f32_16x16x32_bf16(a, Bf[0][s], c0, 0, 0, 0);
        c1 = __builtin_amdgcn_mfma_f32_16x16x32_bf16(a, Bf[1][s], c1, 0, 0, 0);
        c2 = __builtin_amdgcn_mfma_f32_16x16x32_bf16(a, Bf[2][s], c2, 0, 0, 0);
        c3 = __builtin_amdgcn_mfma_f32_16x16x32_bf16(a, Bf[3][s], c3, 0, 0, 0);
    }
    #pragma unroll
    for (int q = 0; q < 4; ++q) {
        Cw[((kg << 2) + q) * 68 +  0 + r] = c0[q];
        Cw[((kg << 2) + q) * 68 + 16 + r] = c1[q];
        Cw[((kg << 2) + q) * 68 + 32 + r] = c2[q];
        Cw[((kg << 2) + q) * 68 + 48 + r] = c3[q];
    }
    #pragma unroll
    for (int i = 0; i < 16; ++i)
        dg[((n0 + i) << 6) | lane] = __float2bfloat16(Cw[i * 68 + lane]);
}

// ---- gather level (+ fused action recompute blocks when DO_ACT) ----------
// gather blocks: cw staged in per-wave LDS; 8 gathers in flight (R19 form).
// act blocks (blockIdx >= gbase): recompute h at action nodes (old k_act).
#define EDGE_FMA(U, A) { \
    float v_ = __bfloat162float(sg[(((size_t)((U) & 0xffffu)) << 6) | lane]); \
    A = fmaf(v_, __int_as_float((int)((U) & 0xffff0000u)), A); }

template <bool DO_GE, bool STORE_H, bool DO_ACT>
__global__ __launch_bounds__(256) void k_gather(const bf16* __restrict__ hW,
        size_t src_stride, const int* __restrict__ ptr,
        const unsigned* __restrict__ cw, const bf16* __restrict__ imbb,
        bf16* __restrict__ hout, float* __restrict__ ge,
        const int* __restrict__ actions, float* __restrict__ act_emb,
        int gblocks) {
    __shared__ unsigned cwbuf[4][CAPW];             // 5 KB
    int lane = threadIdx.x & 63;
    int wv   = threadIdx.x >> 6;

    if (DO_ACT && blockIdx.x >= gblocks) {          // fused action blocks
        int abid = blockIdx.x - gblocks;
        int g    = abid & 7;
        int a    = (abid >> 3) * 4 + wv;
        int node = actions[(size_t)g * A_ACT + a];
        const bf16*     sg  = hW + (size_t)g * N_NODES * D_DIM;
        const int*      pg  = ptr + g * (N_NODES + 1);
        const unsigned* cwg = cw + (size_t)g * E_EDGES;
        int s0 = pg[node], s1 = pg[node + 1];
        float acc = 0.f;
        for (int e = s0; e < s1; ++e) {
            unsigned u = cwg[e];
            EDGE_FMA(u, acc)
        }
        float hv = fmaxf(acc + __bfloat162float(imbb[(node << 6) | lane]), 0.f);
        act_emb[((size_t)g * A_ACT + a) * D_DIM + lane] = hv;
        return;
    }

    int g    = blockIdx.x & 7;
    int chunk = blockIdx.x >> 3;
    const int CH = gblocks >> 3;
    int waves_per_graph = CH * 4;
    int npw = (N_NODES + waves_per_graph - 1) / waves_per_graph;
    int n0 = (chunk * 4 + wv) * npw;
    int n1 = min(n0 + npw, N_NODES);
    if (n0 >= n1) return;

    const bf16*     sg  = hW + (size_t)g * src_stride;
    const int*      pg  = ptr + g * (N_NODES + 1);
    const unsigned* cwg = cw + (size_t)g * E_EDGES;
    bf16* hg = hout + (size_t)g * N_NODES * D_DIM;
    float gsum = 0.f;

    int sb = pg[n0];
    int se = pg[n1];
    int span = se - sb;
    unsigned* wbuf = cwbuf[wv];

    if (span <= CAPW) {
        for (int i = lane; i < span; i += 64)
            wbuf[i] = cwg[sb + i];
        int s0 = sb;
        for (int n = n0; n < n1; ++n) {
            int s1 = pg[n + 1];
            float imv = __bfloat162float(imbb[(n << 6) | lane]);
            float a0 = 0.f, a1 = 0.f, a2 = 0.f, a3 = 0.f;
            int e = s0 - sb;
            int ee = s1 - sb;
            for (; e + 8 <= ee; e += 8) {
                unsigned u0 = wbuf[e],   u1 = wbuf[e+1], u2 = wbuf[e+2], u3 = wbuf[e+3];
                unsigned u4 = wbuf[e+4], u5 = wbuf[e+5], u6 = wbuf[e+6], u7 = wbuf[e+7];
                EDGE_FMA(u0, a0) EDGE_FMA(u1, a1) EDGE_FMA(u2, a2) EDGE_FMA(u3, a3)
                EDGE_FMA(u4, a0) EDGE_FMA(u5, a1) EDGE_FMA(u6, a2) EDGE_FMA(u7, a3)
            }
            for (; e + 2 <= ee; e += 2) {
                unsigned u0 = wbuf[e], u1 = wbuf[e+1];
                EDGE_FMA(u0, a0) EDGE_FMA(u1, a1)
            }
            if (e < ee) {
                unsigned u = wbuf[e];
                EDGE_FMA(u, a2)
            }
            s0 = s1;
            float hv = ((a0 + a1) + (a2 + a3)) + imv;
            hv = fmaxf(hv, 0.f);
            if (STORE_H) hg[((size_t)n << 6) | lane] = __float2bfloat16(hv);
            gsum += hv;
        }
    } else {
        int s0 = sb;
        for (int n = n0; n < n1; ++n) {
            int s1 = pg[n + 1];
            float imv = __bfloat162float(imbb[(n << 6) | lane]);
            float a0 = 0.f, a1 = 0.f, a2 = 0.f, a3 = 0.f;
            int e = s0;
            for (; e + 8 <= s1; e += 8) {
                unsigned u0 = cwg[e],   u1 = cwg[e+1], u2 = cwg[e+2], u3 = cwg[e+3];
                unsigned u4 = cwg[e+4], u5 = cwg[e+5], u6 = cwg[e+6], u7 = cwg[e+7];
                EDGE_FMA(u0, a0) EDGE_FMA(u1, a1) EDGE_FMA(u2, a2) EDGE_FMA(u3, a3)
                EDGE_FMA(u4, a0) EDGE_FMA(u5, a1) EDGE_FMA(u6, a2) EDGE_FMA(u7, a3)
            }
            for (; e + 2 <= s1; e += 2) {
                unsigned u0 = cwg[e], u1 = cwg[e+1];
                EDGE_FMA(u0, a0) EDGE_FMA(u1, a1)
            }
            if (e < s1) {
                unsigned u = cwg[e];
                EDGE_FMA(u, a2)
            }
            s0 = s1;
            float hv = ((a0 + a1) + (a2 + a3)) + imv;
            hv = fmaxf(hv, 0.f);
            if (STORE_H) hg[((size_t)n << 6) | lane] = __float2bfloat16(hv);
            gsum += hv;
        }
    }
    if (DO_GE) atomicAdd(&ge[g * D_DIM + lane], gsum);
}

// ------- raw_pred[b,a]: fused {ge scale + label embed + lin1 + linout} ----
__global__ __launch_bounds__(256) void k_tail(const float* __restrict__ geraw,
        const int* __restrict__ labels,
        const float* __restrict__ le1w, const float* __restrict__ le1b,
        const float* __restrict__ le2w, const float* __restrict__ le2b,
        const float* __restrict__ act_emb,
        const float* __restrict__ lin1w, const float* __restrict__ lin1b,
        const float* __restrict__ loutw, const float* __restrict__ loutb,
        float* __restrict__ raw) {
    __shared__ float Wl[192 * 64];                  // 48 KB
    for (int i = threadIdx.x; i < 192 * 64; i += 256) Wl[i] = lin1w[i];
    __syncthreads();
    int lane = threadIdx.x & 63;
    int wv = blockIdx.x * 4 + (threadIdx.x >> 6);
    if (wv >= B_GR * A_ACT) return;
    int b = wv >> 9;

    // per-wave graph embed (scaled) + label embed, in registers
    float gv = geraw[b * D_DIM + lane] * (1.f / (float)N_NODES);
    float x = le1b[lane];
    #pragma unroll
    for (int i = 0; i < NI_L; ++i) {
        int cls = labels[b * NI_L + i];
        x += le1w[(i * NCLS + cls) * D_DIM + lane];
    }
    x = fmaxf(x, 0.f);
    float lv = le2b[lane];
    for (int hh = 0; hh < D_DIM; ++hh)
        lv = fmaf(__shfl(x, hh), le2w[hh * D_DIM + lane], lv);
    lv = fmaxf(lv, 0.f);

    float e2 = act_emb[(size_t)wv * D_DIM + lane];
    float z = lin1b[lane];
    #pragma unroll 4
    for (int k = 0; k < 64; ++k) z = fmaf(__shfl(gv, k), Wl[k * 64 + lane], z);
    #pragma unroll 4
    for (int k = 0; k < 64; ++k) z = fmaf(__shfl(lv, k), Wl[(64 + k) * 64 + lane], z);
    #pragma unroll 4
    for (int k = 0; k < 64; ++k) z = fmaf(__shfl(e2, k), Wl[(128 + k) * 64 + lane], z);
    z = fmaxf(z, 0.f);
    float r = z * loutw[lane];
    #pragma unroll
    for (int off = 32; off; off >>= 1) r += __shfl_xor(r, off);
    if (lane == 0) raw[wv] = r + loutb[0];
}

// ---------------- preds[b] = max_a raw[b,a] ----------------
__global__ __launch_bounds__(512) void k_max(const float* __restrict__ raw,
        float* __restrict__ out) {
    int b = threadIdx.x >> 6, lane = threadIdx.x & 63;
    float m = -INFINITY;
    for (int a = lane; a < A_ACT; a += 64) m = fmaxf(m, raw[b * A_ACT + a]);
    #pragma unroll
    for (int off = 32; off; off >>= 1) m = fmaxf(m, __shfl_xor(m, off));
    if (lane == 0) out[b] = m;
}

extern "C" void kernel_launch(void* const* d_in, const int* in_sizes, int n_in,
                              void* d_out, int out_size, void* d_ws, size_t ws_size,
                              hipStream_t stream) {
    const float* nf      = (const float*)d_in[0];
    const float* w_n2l   = (const float*)d_in[1];
    const float* bias_n2l= (const float*)d_in[2];
    const float* conv_w  = (const float*)d_in[3];
    const float* conv_b  = (const float*)d_in[4];
    const float* lin1_w  = (const float*)d_in[5];
    const float* lin1_b  = (const float*)d_in[6];
    const float* linout_w= (const float*)d_in[7];
    const float* linout_b= (const float*)d_in[8];
    const float* le1_w   = (const float*)d_in[9];
    const float* le1_b   = (const float*)d_in[10];
    const float* le2_w   = (const float*)d_in[11];
    const float* le2_b   = (const float*)d_in[12];
    const float* edge_w  = (const float*)d_in[13];
    const int*   rows    = (const int*)d_in[14];
    const int*   cols    = (const int*)d_in[15];
    const int*   labels  = (const int*)d_in[16];
    const int*   actions = (const int*)d_in[17];
    float* out = (float*)d_out;

    const size_t NE = (size_t)N_NODES * D_DIM;      // 1.28 M elems

    // ---- workspace carve (~61 MB; 79.8 MB proven safe) ----
    unsigned* cw = (unsigned*)d_ws;                 // 10.24 MB (4B edge records)
    bf16*  h1   = (bf16*)(cw + (size_t)B_GR * E_EDGES);    // 20.5 MB
    float2* temp = (float2*)h1;                     // aliases h1 (consumed pre-gather0)
    bf16*  hW1  = h1 + 8 * NE;                      // 20.5 MB
    bf16*  imbb = hW1 + 8 * NE;                     // 2.56 MB
    bf16*  h0b  = imbb + NE;                        // 2.56 MB
    bf16*  hW0  = h0b + NE;                         // 2.56 MB
    float* act  = (float*)(hW0 + NE);               // 1 MB f32
    float* ge   = act + (size_t)B_GR * A_ACT * D_DIM;
    float* raw  = ge + 512;
    int*   bcnt = (int*)(raw + B_GR * A_ACT);       // 1280
    int*   bptr = bcnt + B_GR * NBUK;               // 1288
    int*   bcur = bptr + B_GR * (NBUK + 1);         // 1280
    int*   ptr  = bcur + B_GR * NBUK;               // 160008 (640 KB)

    // ---- prologue ----
    k_n2l<<<512, 256, 0, stream>>>(nf, w_n2l, bias_n2l, conv_b, imbb, h0b);
    hipMemsetAsync(bcnt, 0, (size_t)B_GR * NBUK * sizeof(int), stream);
    hipMemsetAsync(ge, 0, 512 * sizeof(float), stream);

    // ---- CSR build: bucket count -> scan -> partition -> LDS sort ----
    k_bcnt<<<1024, 256, 0, stream>>>(rows, bcnt);
    k_bscan<<<B_GR, 256, 0, stream>>>(bcnt, bptr, bcur);

    // hW0 = h0 @ W (independent of CSR build)
    k_gemm<1><<<313, 256, 0, stream>>>(h0b, conv_w, hW0);

    k_part<<<1024, 256, 0, stream>>>(rows, cols, edge_w, bcur, temp);
    k_scat3<<<NBUK * 8, 256, 0, stream>>>(temp, bptr, ptr, cw);

    // ---- level 0: h1 = relu(A_g @ hW0 + imb) ----
    k_gather<false, true, false><<<512 * 8, 256, 0, stream>>>(
            hW0, 0, ptr, cw, imbb, h1, nullptr, nullptr, nullptr, 512 * 8);

    // hW1 = h1 @ W (per graph)
    k_gemm<8><<<313 * 8, 256, 0, stream>>>(h1, conv_w, hW1);

    // ---- level 1 + fused action recompute (1024 extra blocks) ----
    k_gather<true, false, true><<<512 * 8 + (A_ACT / 4) * 8, 256, 0, stream>>>(
            hW1, NE, ptr, cw, imbb, nullptr, ge, actions, act, 512 * 8);

    // ---- fused tail (ge scale + label embed inline) ----
    k_tail<<<(B_GR * A_ACT) / 4, 256, 0, stream>>>(ge, labels, le1_w, le1_b,
            le2_w, le2_b, act, lin1_w, lin1_b, linout_w, linout_b, raw);
    k_max<<<1, 512, 0, stream>>>(raw, out);
}